// Round 1
// baseline (564.556 us; speedup 1.0000x reference)
//
#include <hip/hip_runtime.h>

typedef float   f32x4 __attribute__((ext_vector_type(4)));
typedef _Float16 f16x8 __attribute__((ext_vector_type(8)));

#define DEV static __device__ __forceinline__

// ---- problem constants ----
#define BB 4
#define TT 32
#define DD 768
#define SS 256          // Hp*Wp
#define NH 12
#define HD 64
#define NSLAB (BB*TT)   // 128 (b,t) slabs
#define NSEQ  (BB*SS)   // 1024 sequences
#define MTOK  (NSEQ*TT) // 32768 tokens
#define NQKV  (3*DD)    // 2304

DEV void async_copy16(const _Float16* g, _Float16* l) {
  __builtin_amdgcn_global_load_lds(
      (const __attribute__((address_space(1))) unsigned int*)g,
      (__attribute__((address_space(3))) unsigned int*)l,
      16, 0, 0);
}

// ---------------------------------------------------------------------------
// K0a: h (B,T,D,Hp,Wp) fp32  ->  A[m=slab*256+s][d] f16   (transpose d<->s)
// grid (128 slabs, 12 d-chunks), 256 thr. LDS tile [256 s][65 d-pad] f16.
// ---------------------------------------------------------------------------
__global__ __launch_bounds__(256) void k_transpose_h(const float* __restrict__ h,
                                                     _Float16* __restrict__ A) {
  __shared__ _Float16 Tl[256 * 65];
  const int slab = blockIdx.x;
  const int d0   = blockIdx.y * 64;
  const int t    = threadIdx.x;
  const float4* hv = (const float4*)(h + (slab * DD + d0) * SS);
  #pragma unroll
  for (int i = 0; i < 16; ++i) {
    int dd = i * 4 + (t >> 6);
    int s4 = (t & 63) * 4;
    float4 v = hv[dd * 64 + (t & 63)];           // coalesced 1KB/wave
    Tl[(s4 + 0) * 65 + dd] = (_Float16)v.x;
    Tl[(s4 + 1) * 65 + dd] = (_Float16)v.y;
    Tl[(s4 + 2) * 65 + dd] = (_Float16)v.z;
    Tl[(s4 + 3) * 65 + dd] = (_Float16)v.w;
  }
  __syncthreads();
  #pragma unroll
  for (int p = 0; p < 8; ++p) {
    int s  = p * 32 + (t >> 3);
    int dd = (t & 7) * 8;
    f16x8 val;
    #pragma unroll
    for (int j = 0; j < 8; ++j) val[j] = Tl[s * 65 + dd + j];
    *(f16x8*)(A + (slab * SS + s) * DD + d0 + dd) = val;   // 16B store
  }
}

// ---------------------------------------------------------------------------
// K0b: weights fp32 -> f16.  WQKV[n][d] n<768:Wq, <1536:Wk, <2304:Wv ; WoH.
// ---------------------------------------------------------------------------
__global__ __launch_bounds__(256) void k_convert_w(const float* __restrict__ Wq,
                                                   const float* __restrict__ Wk,
                                                   const float* __restrict__ Wv,
                                                   const float* __restrict__ Wo,
                                                   _Float16* __restrict__ WQKV,
                                                   _Float16* __restrict__ WoH) {
  int idx = blockIdx.x * 256 + threadIdx.x;     // 3072*96 tasks, 8 elems each
  int row = idx / 96;
  int c8  = (idx % 96) * 8;
  const float* src; _Float16* dst;
  if (row < 768)       { src = Wq + row * 768;          dst = WQKV + row * 768; }
  else if (row < 1536) { src = Wk + (row - 768) * 768;  dst = WQKV + row * 768; }
  else if (row < 2304) { src = Wv + (row - 1536) * 768; dst = WQKV + row * 768; }
  else                 { src = Wo + (row - 2304) * 768; dst = WoH  + (row - 2304) * 768; }
  float4 v0 = *(const float4*)(src + c8);
  float4 v1 = *(const float4*)(src + c8 + 4);
  f16x8 o;
  o[0]=(_Float16)v0.x; o[1]=(_Float16)v0.y; o[2]=(_Float16)v0.z; o[3]=(_Float16)v0.w;
  o[4]=(_Float16)v1.x; o[5]=(_Float16)v1.y; o[6]=(_Float16)v1.z; o[7]=(_Float16)v1.w;
  *(f16x8*)(dst + c8) = o;
}

// ---------------------------------------------------------------------------
// K1: u_pen[(b*256+s)*32 + t] = lam[(b,t),s] * mean_d u[(b,t),d,s]
// grid 512: (slab, d-quarter) ; atomicAdd into zeroed upen.
// ---------------------------------------------------------------------------
__global__ __launch_bounds__(256) void k_upen(const float* __restrict__ u,
                                              const float* __restrict__ lam,
                                              float* __restrict__ upen) {
  int slab = blockIdx.x >> 2;
  int q    = blockIdx.x & 3;
  int s    = threadIdx.x;
  const float* base = u + (slab * DD + q * 192) * SS + s;
  float sum = 0.f;
  for (int d = 0; d < 192; ++d) sum += base[d * SS];   // coalesced across s
  int b = slab >> 5, tt = slab & 31;
  float l = lam[slab * SS + s];
  atomicAdd(&upen[(b * SS + s) * TT + tt], sum * l * (1.0f / 768.0f));
}

// ---------------------------------------------------------------------------
// K2: QKV GEMM.  C[m][n] = A[m][:] . WQKV[n][:] + bias(n), Q-part scaled 1/8.
// 128x128 tile, BK=32, 4 waves, 16x16x32 f16 MFMA, global_load_lds width 16.
// ---------------------------------------------------------------------------
__global__ __launch_bounds__(256) void k_gemm_qkv(const _Float16* __restrict__ A,
                                                  const _Float16* __restrict__ Bw,
                                                  const float* __restrict__ bq,
                                                  const float* __restrict__ bk,
                                                  const float* __restrict__ bv,
                                                  _Float16* __restrict__ QKV) {
  __shared__ _Float16 As[128 * 32];
  __shared__ _Float16 Bs[128 * 32];
  const int nt = blockIdx.x % 18, mt = blockIdx.x / 18;
  const int m0 = mt * 128, n0 = nt * 128;
  const int tid = threadIdx.x, w = tid >> 6, lane = tid & 63;
  const int wr = (w >> 1) * 64, wc = (w & 1) * 64;
  f32x4 acc[4][4] = {};
  for (int it = 0; it < 24; ++it) {
    const int k0 = it * 32;
    __syncthreads();
    #pragma unroll
    for (int i = 0; i < 2; ++i) {
      int c = tid + 256 * i;
      int row = c >> 2, coff = (c & 3) * 8;
      _Float16* ldsA = (_Float16*)((char*)As + w * 1024 + i * 4096 + lane * 16);
      _Float16* ldsB = (_Float16*)((char*)Bs + w * 1024 + i * 4096 + lane * 16);
      async_copy16(A  + (m0 + row) * DD + k0 + coff, ldsA);
      async_copy16(Bw + (n0 + row) * DD + k0 + coff, ldsB);
    }
    __syncthreads();
    f16x8 af[4], bf[4];
    #pragma unroll
    for (int mi = 0; mi < 4; ++mi)
      af[mi] = *(const f16x8*)&As[(wr + mi * 16 + (lane & 15)) * 32 + (lane >> 4) * 8];
    #pragma unroll
    for (int ni = 0; ni < 4; ++ni)
      bf[ni] = *(const f16x8*)&Bs[(wc + ni * 16 + (lane & 15)) * 32 + (lane >> 4) * 8];
    #pragma unroll
    for (int mi = 0; mi < 4; ++mi)
      #pragma unroll
      for (int ni = 0; ni < 4; ++ni)
        acc[mi][ni] = __builtin_amdgcn_mfma_f32_16x16x32_f16(af[mi], bf[ni], acc[mi][ni], 0, 0, 0);
  }
  #pragma unroll
  for (int ni = 0; ni < 4; ++ni) {
    int n = n0 + wc + ni * 16 + (lane & 15);
    float bias, scale = 1.0f;
    if (n < 768)       { bias = bq[n];        scale = 0.125f; }   // fold 1/sqrt(64) into Q
    else if (n < 1536) { bias = bk[n - 768]; }
    else               { bias = bv[n - 1536]; }
    #pragma unroll
    for (int mi = 0; mi < 4; ++mi) {
      int mbase = m0 + wr + mi * 16 + (lane >> 4) * 4;
      f32x4 v = acc[mi][ni];
      #pragma unroll
      for (int r = 0; r < 4; ++r)
        QKV[(mbase + r) * NQKV + n] = (_Float16)((v[r] + bias) * scale);
    }
  }
}

// ---------------------------------------------------------------------------
// K3: attention. 1 wave per (seq, head); block = 4 waves; grid = 1024*3.
// Q/K frags straight from global; V + P via per-wave LDS; shuffle softmax.
// O written into Abuf (A no longer needed).
// ---------------------------------------------------------------------------
__global__ __launch_bounds__(256) void k_attn(const _Float16* __restrict__ QKV,
                                              const float* __restrict__ upen,
                                              _Float16* __restrict__ O) {
  __shared__ _Float16 lds[4][32 * 64 + 32 * 40];   // per-wave: Vs[32][64], Ps[32][40]
  const int w = threadIdx.x >> 6, lane = threadIdx.x & 63;
  const int seq = blockIdx.x / 3, hg = blockIdx.x % 3;
  const int head = hg * 4 + w;
  const int b = seq >> 8, s = seq & 255;
  _Float16* Vs = &lds[w][0];
  _Float16* Ps = &lds[w][32 * 64];
  const _Float16* qptr = QKV + head * HD;
  const _Float16* kptr = QKV + DD + head * HD;
  const _Float16* vptr = QKV + 2 * DD + head * HD;
  #define MROW(t_) ((((b << 5) + (t_)) * SS + s) * NQKV)

  // stage V rows (t, hd-contig) into LDS
  #pragma unroll
  for (int p = 0; p < 4; ++p) {
    int t  = p * 8 + (lane >> 3);
    int cc = (lane & 7) * 8;
    *(f16x8*)(Vs + t * 64 + cc) = *(const f16x8*)(vptr + MROW(t) + cc);
  }
  // Q / K fragments direct from global (a/b-frag layout: m|n = lane&15, k = (lane>>4)*8+j)
  f16x8 qf[2][2], kf[2][2];
  #pragma unroll
  for (int i = 0; i < 2; ++i)
    #pragma unroll
    for (int ks = 0; ks < 2; ++ks) {
      int t  = i * 16 + (lane & 15);
      int kk = ks * 32 + (lane >> 4) * 8;
      qf[i][ks] = *(const f16x8*)(qptr + MROW(t) + kk);
      kf[i][ks] = *(const f16x8*)(kptr + MROW(t) + kk);
    }
  // scores = (Q/8) . K^T   (2x2 tiles of 16x16, K=64)
  f32x4 sc[2][2] = {};
  #pragma unroll
  for (int mq = 0; mq < 2; ++mq)
    #pragma unroll
    for (int nk = 0; nk < 2; ++nk)
      #pragma unroll
      for (int ks = 0; ks < 2; ++ks)
        sc[mq][nk] = __builtin_amdgcn_mfma_f32_16x16x32_f16(qf[mq][ks], kf[nk][ks], sc[mq][nk], 0, 0, 0);

  const float up0 = upen[seq * TT + (lane & 15)];
  const float up1 = upen[seq * TT + 16 + (lane & 15)];

  // softmax over 32 keys per query row; rows live in (reg, lane>>4); cols in lane&15 x nk
  #pragma unroll
  for (int mq = 0; mq < 2; ++mq) {
    #pragma unroll
    for (int r = 0; r < 4; ++r) {
      float s0 = sc[mq][0][r] - up0;
      float s1 = sc[mq][1][r] - up1;
      float mx = fmaxf(s0, s1);
      #pragma unroll
      for (int off = 1; off < 16; off <<= 1) mx = fmaxf(mx, __shfl_xor(mx, off, 64));
      float e0 = __expf(s0 - mx), e1 = __expf(s1 - mx);
      float sum = e0 + e1;
      #pragma unroll
      for (int off = 1; off < 16; off <<= 1) sum += __shfl_xor(sum, off, 64);
      float inv = 1.0f / sum;
      int row = mq * 16 + (lane >> 4) * 4 + r;
      Ps[row * 40 + (lane & 15)]      = (_Float16)(e0 * inv);
      Ps[row * 40 + 16 + (lane & 15)] = (_Float16)(e1 * inv);
    }
  }
  // PV: out[32q][64hd] = P[32x32] @ V[32x64] ; K=32 -> one MFMA per (mq,nh)
  f16x8 pf[2];
  #pragma unroll
  for (int mq = 0; mq < 2; ++mq)
    pf[mq] = *(const f16x8*)(Ps + (mq * 16 + (lane & 15)) * 40 + (lane >> 4) * 8);
  f32x4 oacc[2][4] = {};
  #pragma unroll
  for (int nh = 0; nh < 4; ++nh) {
    int hd = nh * 16 + (lane & 15);
    f16x8 vf;
    #pragma unroll
    for (int j = 0; j < 8; ++j) vf[j] = Vs[((lane >> 4) * 8 + j) * 64 + hd];  // transpose gather
    #pragma unroll
    for (int mq = 0; mq < 2; ++mq)
      oacc[mq][nh] = __builtin_amdgcn_mfma_f32_16x16x32_f16(pf[mq], vf, oacc[mq][nh], 0, 0, 0);
  }
  // write O[m][head*64+hd] f16 (token-major, k-contiguous for final GEMM)
  #pragma unroll
  for (int mq = 0; mq < 2; ++mq)
    #pragma unroll
    for (int nh = 0; nh < 4; ++nh) {
      int hd = nh * 16 + (lane & 15);
      #pragma unroll
      for (int r = 0; r < 4; ++r) {
        int t = mq * 16 + (lane >> 4) * 4 + r;
        O[(((b << 5) + t) * SS + s) * DD + head * HD + hd] = (_Float16)oacc[mq][nh][r];
      }
    }
  #undef MROW
}

// ---------------------------------------------------------------------------
// K4: output GEMM, swapped operands: C'[n][token] = Wo[n][:] . O[token][:] + bo[n]
// -> writes final (B,T,D,Hp,Wp) fp32 with s-contiguous coalesced stores.
// ---------------------------------------------------------------------------
__global__ __launch_bounds__(256) void k_gemm_out(const _Float16* __restrict__ Wn,
                                                  const _Float16* __restrict__ O,
                                                  const float* __restrict__ bo,
                                                  float* __restrict__ out) {
  __shared__ _Float16 As[128 * 32];   // Wo rows (n, k)
  __shared__ _Float16 Bs[128 * 32];   // O rows (token, k)
  const int rt = blockIdx.x % 6, ct = blockIdx.x / 6;
  const int R0 = rt * 128, C0 = ct * 128;
  const int tid = threadIdx.x, w = tid >> 6, lane = tid & 63;
  const int wr = (w >> 1) * 64, wc = (w & 1) * 64;
  f32x4 acc[4][4] = {};
  for (int it = 0; it < 24; ++it) {
    const int k0 = it * 32;
    __syncthreads();
    #pragma unroll
    for (int i = 0; i < 2; ++i) {
      int c = tid + 256 * i;
      int row = c >> 2, coff = (c & 3) * 8;
      _Float16* ldsA = (_Float16*)((char*)As + w * 1024 + i * 4096 + lane * 16);
      _Float16* ldsB = (_Float16*)((char*)Bs + w * 1024 + i * 4096 + lane * 16);
      async_copy16(Wn + (R0 + row) * DD + k0 + coff, ldsA);
      async_copy16(O  + (C0 + row) * DD + k0 + coff, ldsB);
    }
    __syncthreads();
    f16x8 af[4], bf[4];
    #pragma unroll
    for (int ri = 0; ri < 4; ++ri)
      af[ri] = *(const f16x8*)&As[(wr + ri * 16 + (lane & 15)) * 32 + (lane >> 4) * 8];
    #pragma unroll
    for (int ci = 0; ci < 4; ++ci)
      bf[ci] = *(const f16x8*)&Bs[(wc + ci * 16 + (lane & 15)) * 32 + (lane >> 4) * 8];
    #pragma unroll
    for (int ri = 0; ri < 4; ++ri)
      #pragma unroll
      for (int ci = 0; ci < 4; ++ci)
        acc[ri][ci] = __builtin_amdgcn_mfma_f32_16x16x32_f16(af[ri], bf[ci], acc[ri][ci], 0, 0, 0);
  }
  const int slab  = C0 >> 8;          // all 128 tokens of tile share one (b,t) slab
  const int sbase = C0 & 255;
  #pragma unroll
  for (int ri = 0; ri < 4; ++ri) {
    #pragma unroll
    for (int ci = 0; ci < 4; ++ci) {
      int s = sbase + wc + ci * 16 + (lane & 15);
      f32x4 v = acc[ri][ci];
      #pragma unroll
      for (int r = 0; r < 4; ++r) {
        int R = R0 + wr + ri * 16 + (lane >> 4) * 4 + r;
        out[(slab * DD + R) * SS + s] = v[r] + bo[R];   // 16 lanes -> 64B contiguous
      }
    }
  }
}

// ---------------------------------------------------------------------------
// host launcher.  ws layout (needs ~197 MiB):
//   [0)              A f16 [32768][768]   (reused as O after QKV GEMM)
//   [50331648)       WQKV f16 [2304][768]
//   [53870592)       Wo   f16 [768][768]
//   [55050240)       upen f32 [32768]
//   [55181312)       QKV  f16 [32768][2304]
// ---------------------------------------------------------------------------
extern "C" void kernel_launch(void* const* d_in, const int* in_sizes, int n_in,
                              void* d_out, int out_size, void* d_ws, size_t ws_size,
                              hipStream_t stream) {
  const float* h   = (const float*)d_in[0];
  const float* u   = (const float*)d_in[1];
  const float* lam = (const float*)d_in[2];
  const float* Wq  = (const float*)d_in[3];
  const float* bq  = (const float*)d_in[4];
  const float* Wk  = (const float*)d_in[5];
  const float* bk  = (const float*)d_in[6];
  const float* Wv  = (const float*)d_in[7];
  const float* bv  = (const float*)d_in[8];
  const float* Wo  = (const float*)d_in[9];
  const float* bo  = (const float*)d_in[10];
  float* out = (float*)d_out;

  char* ws = (char*)d_ws;
  _Float16* Abuf = (_Float16*)(ws);
  _Float16* WQKV = (_Float16*)(ws + 50331648);
  _Float16* WoH  = (_Float16*)(ws + 53870592);
  float*    upen = (float*)   (ws + 55050240);
  _Float16* QKV  = (_Float16*)(ws + 55181312);

  hipMemsetAsync(upen, 0, MTOK * sizeof(float) / TT * TT ? 32768 * sizeof(float) : 0, stream);
  k_transpose_h<<<dim3(128, 12), 256, 0, stream>>>(h, Abuf);
  k_convert_w<<<1152, 256, 0, stream>>>(Wq, Wk, Wv, Wo, WQKV, WoH);
  k_upen<<<512, 256, 0, stream>>>(u, lam, upen);
  k_gemm_qkv<<<256 * 18, 256, 0, stream>>>(Abuf, WQKV, bq, bk, bv, QKV);
  k_attn<<<1024 * 3, 256, 0, stream>>>(QKV, upen, Abuf);
  k_gemm_out<<<256 * 6, 256, 0, stream>>>(WoH, Abuf, bo, out);
}

// Round 2
// 533.891 us; speedup vs baseline: 1.0574x; 1.0574x over previous
//
#include <hip/hip_runtime.h>

typedef float   f32x4 __attribute__((ext_vector_type(4)));
typedef _Float16 f16x8 __attribute__((ext_vector_type(8)));

#define DEV static __device__ __forceinline__

// ---- problem constants ----
#define BB 4
#define TT 32
#define DD 768
#define SS 256          // Hp*Wp
#define NH 12
#define HD 64
#define NSLAB (BB*TT)   // 128 (b,t) slabs
#define NSEQ  (BB*SS)   // 1024 sequences
#define MTOK  (NSEQ*TT) // 32768 tokens
#define NQKV  (3*DD)    // 2304

DEV void async_copy16(const _Float16* g, _Float16* l) {
  __builtin_amdgcn_global_load_lds(
      (const __attribute__((address_space(1))) unsigned int*)g,
      (__attribute__((address_space(3))) unsigned int*)l,
      16, 0, 0);
}

// XOR-swizzled LDS 16B-chunk index for a [128 rows][4 chunks] tile.
// Read side (16 consecutive rows, fixed kc) hits every bank-quad exactly
// twice -> conflict-free (2-way is free on CDNA4).
DEV int swz_chunk(int r, int kc) {
  return r * 4 + (kc ^ (r & 3) ^ ((r >> 2) & 3));
}

// ---------------------------------------------------------------------------
// K0a: h (B,T,D,Hp,Wp) fp32  ->  A[m=slab*256+s][d] f16   (transpose d<->s)
// grid (128 slabs, 12 d-chunks), 256 thr. LDS tile [256 s][65 d-pad] f16.
// ---------------------------------------------------------------------------
__global__ __launch_bounds__(256) void k_transpose_h(const float* __restrict__ h,
                                                     _Float16* __restrict__ A) {
  __shared__ _Float16 Tl[256 * 65];
  const int slab = blockIdx.x;
  const int d0   = blockIdx.y * 64;
  const int t    = threadIdx.x;
  const float4* hv = (const float4*)(h + (slab * DD + d0) * SS);
  #pragma unroll
  for (int i = 0; i < 16; ++i) {
    int dd = i * 4 + (t >> 6);
    int s4 = (t & 63) * 4;
    float4 v = hv[dd * 64 + (t & 63)];           // coalesced 1KB/wave
    Tl[(s4 + 0) * 65 + dd] = (_Float16)v.x;
    Tl[(s4 + 1) * 65 + dd] = (_Float16)v.y;
    Tl[(s4 + 2) * 65 + dd] = (_Float16)v.z;
    Tl[(s4 + 3) * 65 + dd] = (_Float16)v.w;
  }
  __syncthreads();
  #pragma unroll
  for (int p = 0; p < 8; ++p) {
    int s  = p * 32 + (t >> 3);
    int dd = (t & 7) * 8;
    f16x8 val;
    #pragma unroll
    for (int j = 0; j < 8; ++j) val[j] = Tl[s * 65 + dd + j];
    *(f16x8*)(A + (slab * SS + s) * DD + d0 + dd) = val;   // 16B store
  }
}

// ---------------------------------------------------------------------------
// K0b: weights fp32 -> f16.  WQKV[n][d] n<768:Wq, <1536:Wk, <2304:Wv ; WoH.
// ---------------------------------------------------------------------------
__global__ __launch_bounds__(256) void k_convert_w(const float* __restrict__ Wq,
                                                   const float* __restrict__ Wk,
                                                   const float* __restrict__ Wv,
                                                   const float* __restrict__ Wo,
                                                   _Float16* __restrict__ WQKV,
                                                   _Float16* __restrict__ WoH) {
  int idx = blockIdx.x * 256 + threadIdx.x;     // 3072*96 tasks, 8 elems each
  int row = idx / 96;
  int c8  = (idx % 96) * 8;
  const float* src; _Float16* dst;
  if (row < 768)       { src = Wq + row * 768;          dst = WQKV + row * 768; }
  else if (row < 1536) { src = Wk + (row - 768) * 768;  dst = WQKV + row * 768; }
  else if (row < 2304) { src = Wv + (row - 1536) * 768; dst = WQKV + row * 768; }
  else                 { src = Wo + (row - 2304) * 768; dst = WoH  + (row - 2304) * 768; }
  float4 v0 = *(const float4*)(src + c8);
  float4 v1 = *(const float4*)(src + c8 + 4);
  f16x8 o;
  o[0]=(_Float16)v0.x; o[1]=(_Float16)v0.y; o[2]=(_Float16)v0.z; o[3]=(_Float16)v0.w;
  o[4]=(_Float16)v1.x; o[5]=(_Float16)v1.y; o[6]=(_Float16)v1.z; o[7]=(_Float16)v1.w;
  *(f16x8*)(dst + c8) = o;
}

// ---------------------------------------------------------------------------
// K1: u_pen[(b*256+s)*32 + t] = lam[(b,t),s] * mean_d u[(b,t),d,s]
// grid 512: (slab, d-quarter) ; atomicAdd into zeroed upen.
// ---------------------------------------------------------------------------
__global__ __launch_bounds__(256) void k_upen(const float* __restrict__ u,
                                              const float* __restrict__ lam,
                                              float* __restrict__ upen) {
  int slab = blockIdx.x >> 2;
  int q    = blockIdx.x & 3;
  int s    = threadIdx.x;
  const float* base = u + (slab * DD + q * 192) * SS + s;
  float sum = 0.f;
  for (int d = 0; d < 192; ++d) sum += base[d * SS];   // coalesced across s
  int b = slab >> 5, tt = slab & 31;
  float l = lam[slab * SS + s];
  atomicAdd(&upen[(b * SS + s) * TT + tt], sum * l * (1.0f / 768.0f));
}

// ---------------------------------------------------------------------------
// K2: QKV GEMM.  C[m][n] = A[m][:] . WQKV[n][:] + bias(n), Q-part scaled 1/8.
// 128x128 tile, BK=32, 4 waves, 16x16x32 f16 MFMA, global_load_lds width 16.
// Block order mt-fastest: same-mt blocks land on same XCD (256%8==0) so the
// A-tile is fetched from HBM once per XCD; W stays L2-resident.
// ---------------------------------------------------------------------------
__global__ __launch_bounds__(256) void k_gemm_qkv(const _Float16* __restrict__ A,
                                                  const _Float16* __restrict__ Bw,
                                                  const float* __restrict__ bq,
                                                  const float* __restrict__ bk,
                                                  const float* __restrict__ bv,
                                                  _Float16* __restrict__ QKV) {
  __shared__ _Float16 As[128 * 32];
  __shared__ _Float16 Bs[128 * 32];
  const int mt = blockIdx.x & 255, nt = blockIdx.x >> 8;   // mt-fastest
  const int m0 = mt * 128, n0 = nt * 128;
  const int tid = threadIdx.x, w = tid >> 6, lane = tid & 63;
  const int wr = (w >> 1) * 64, wc = (w & 1) * 64;
  f32x4 acc[4][4] = {};
  for (int it = 0; it < 24; ++it) {
    const int k0 = it * 32;
    __syncthreads();
    #pragma unroll
    for (int i = 0; i < 2; ++i) {
      int c = tid + 256 * i;
      int row = c >> 2;
      int coff = ((c & 3) ^ (row & 3) ^ ((row >> 2) & 3)) * 8;   // XOR swizzle
      _Float16* ldsA = (_Float16*)((char*)As + w * 1024 + i * 4096 + lane * 16);
      _Float16* ldsB = (_Float16*)((char*)Bs + w * 1024 + i * 4096 + lane * 16);
      async_copy16(A  + (m0 + row) * DD + k0 + coff, ldsA);
      async_copy16(Bw + (n0 + row) * DD + k0 + coff, ldsB);
    }
    __syncthreads();
    f16x8 af[4], bf[4];
    #pragma unroll
    for (int mi = 0; mi < 4; ++mi)
      af[mi] = *(const f16x8*)&As[swz_chunk(wr + mi * 16 + (lane & 15), lane >> 4) * 8];
    #pragma unroll
    for (int ni = 0; ni < 4; ++ni)
      bf[ni] = *(const f16x8*)&Bs[swz_chunk(wc + ni * 16 + (lane & 15), lane >> 4) * 8];
    #pragma unroll
    for (int mi = 0; mi < 4; ++mi)
      #pragma unroll
      for (int ni = 0; ni < 4; ++ni)
        acc[mi][ni] = __builtin_amdgcn_mfma_f32_16x16x32_f16(af[mi], bf[ni], acc[mi][ni], 0, 0, 0);
  }
  #pragma unroll
  for (int ni = 0; ni < 4; ++ni) {
    int n = n0 + wc + ni * 16 + (lane & 15);
    float bias, scale = 1.0f;
    if (n < 768)       { bias = bq[n];        scale = 0.125f; }   // fold 1/sqrt(64) into Q
    else if (n < 1536) { bias = bk[n - 768]; }
    else               { bias = bv[n - 1536]; }
    #pragma unroll
    for (int mi = 0; mi < 4; ++mi) {
      int mbase = m0 + wr + mi * 16 + (lane >> 4) * 4;
      f32x4 v = acc[mi][ni];
      #pragma unroll
      for (int r = 0; r < 4; ++r)
        QKV[(mbase + r) * NQKV + n] = (_Float16)((v[r] + bias) * scale);
    }
  }
}

// ---------------------------------------------------------------------------
// K3: attention. 1 wave per (seq, head); block = 4 waves; grid = 1024*3.
// Q/K frags straight from global; V + P via per-wave LDS; shuffle softmax.
// O written into Abuf (A no longer needed).
// ---------------------------------------------------------------------------
__global__ __launch_bounds__(256) void k_attn(const _Float16* __restrict__ QKV,
                                              const float* __restrict__ upen,
                                              _Float16* __restrict__ O) {
  __shared__ _Float16 lds[4][32 * 64 + 32 * 40];   // per-wave: Vs[32][64], Ps[32][40]
  const int w = threadIdx.x >> 6, lane = threadIdx.x & 63;
  const int seq = blockIdx.x / 3, hg = blockIdx.x % 3;
  const int head = hg * 4 + w;
  const int b = seq >> 8, s = seq & 255;
  _Float16* Vs = &lds[w][0];
  _Float16* Ps = &lds[w][32 * 64];
  const _Float16* qptr = QKV + head * HD;
  const _Float16* kptr = QKV + DD + head * HD;
  const _Float16* vptr = QKV + 2 * DD + head * HD;
  #define MROW(t_) ((((b << 5) + (t_)) * SS + s) * NQKV)

  // stage V rows (t, hd-contig) into LDS
  #pragma unroll
  for (int p = 0; p < 4; ++p) {
    int t  = p * 8 + (lane >> 3);
    int cc = (lane & 7) * 8;
    *(f16x8*)(Vs + t * 64 + cc) = *(const f16x8*)(vptr + MROW(t) + cc);
  }
  // Q / K fragments direct from global (a/b-frag layout: m|n = lane&15, k = (lane>>4)*8+j)
  f16x8 qf[2][2], kf[2][2];
  #pragma unroll
  for (int i = 0; i < 2; ++i)
    #pragma unroll
    for (int ks = 0; ks < 2; ++ks) {
      int t  = i * 16 + (lane & 15);
      int kk = ks * 32 + (lane >> 4) * 8;
      qf[i][ks] = *(const f16x8*)(qptr + MROW(t) + kk);
      kf[i][ks] = *(const f16x8*)(kptr + MROW(t) + kk);
    }
  // scores = (Q/8) . K^T   (2x2 tiles of 16x16, K=64)
  f32x4 sc[2][2] = {};
  #pragma unroll
  for (int mq = 0; mq < 2; ++mq)
    #pragma unroll
    for (int nk = 0; nk < 2; ++nk)
      #pragma unroll
      for (int ks = 0; ks < 2; ++ks)
        sc[mq][nk] = __builtin_amdgcn_mfma_f32_16x16x32_f16(qf[mq][ks], kf[nk][ks], sc[mq][nk], 0, 0, 0);

  const float up0 = upen[seq * TT + (lane & 15)];
  const float up1 = upen[seq * TT + 16 + (lane & 15)];

  // softmax over 32 keys per query row; rows live in (reg, lane>>4); cols in lane&15 x nk
  #pragma unroll
  for (int mq = 0; mq < 2; ++mq) {
    #pragma unroll
    for (int r = 0; r < 4; ++r) {
      float s0 = sc[mq][0][r] - up0;
      float s1 = sc[mq][1][r] - up1;
      float mx = fmaxf(s0, s1);
      #pragma unroll
      for (int off = 1; off < 16; off <<= 1) mx = fmaxf(mx, __shfl_xor(mx, off, 64));
      float e0 = __expf(s0 - mx), e1 = __expf(s1 - mx);
      float sum = e0 + e1;
      #pragma unroll
      for (int off = 1; off < 16; off <<= 1) sum += __shfl_xor(sum, off, 64);
      float inv = 1.0f / sum;
      int row = mq * 16 + (lane >> 4) * 4 + r;
      Ps[row * 40 + (lane & 15)]      = (_Float16)(e0 * inv);
      Ps[row * 40 + 16 + (lane & 15)] = (_Float16)(e1 * inv);
    }
  }
  // PV: out[32q][64hd] = P[32x32] @ V[32x64] ; K=32 -> one MFMA per (mq,nh)
  f16x8 pf[2];
  #pragma unroll
  for (int mq = 0; mq < 2; ++mq)
    pf[mq] = *(const f16x8*)(Ps + (mq * 16 + (lane & 15)) * 40 + (lane >> 4) * 8);
  f32x4 oacc[2][4] = {};
  #pragma unroll
  for (int nh = 0; nh < 4; ++nh) {
    int hd = nh * 16 + (lane & 15);
    f16x8 vf;
    #pragma unroll
    for (int j = 0; j < 8; ++j) vf[j] = Vs[((lane >> 4) * 8 + j) * 64 + hd];  // transpose gather
    #pragma unroll
    for (int mq = 0; mq < 2; ++mq)
      oacc[mq][nh] = __builtin_amdgcn_mfma_f32_16x16x32_f16(pf[mq], vf, oacc[mq][nh], 0, 0, 0);
  }
  // write O[m][head*64+hd] f16 (token-major, k-contiguous for final GEMM)
  #pragma unroll
  for (int mq = 0; mq < 2; ++mq)
    #pragma unroll
    for (int nh = 0; nh < 4; ++nh) {
      int hd = nh * 16 + (lane & 15);
      #pragma unroll
      for (int r = 0; r < 4; ++r) {
        int t = mq * 16 + (lane >> 4) * 4 + r;
        O[(((b << 5) + t) * SS + s) * DD + head * HD + hd] = (_Float16)oacc[mq][nh][r];
      }
    }
  #undef MROW
}

// ---------------------------------------------------------------------------
// K4: output GEMM, swapped operands: C'[n][token] = Wo[n][:] . O[token][:] + bo[n]
// -> writes final (B,T,D,Hp,Wp) fp32 with s-contiguous coalesced stores.
// Block order ct-fastest: same-ct blocks share an XCD -> O-tile fetched once.
// ---------------------------------------------------------------------------
__global__ __launch_bounds__(256) void k_gemm_out(const _Float16* __restrict__ Wn,
                                                  const _Float16* __restrict__ O,
                                                  const float* __restrict__ bo,
                                                  float* __restrict__ out) {
  __shared__ _Float16 As[128 * 32];   // Wo rows (n, k)
  __shared__ _Float16 Bs[128 * 32];   // O rows (token, k)
  const int ct = blockIdx.x & 255, rt = blockIdx.x >> 8;   // ct-fastest
  const int R0 = rt * 128, C0 = ct * 128;
  const int tid = threadIdx.x, w = tid >> 6, lane = tid & 63;
  const int wr = (w >> 1) * 64, wc = (w & 1) * 64;
  f32x4 acc[4][4] = {};
  for (int it = 0; it < 24; ++it) {
    const int k0 = it * 32;
    __syncthreads();
    #pragma unroll
    for (int i = 0; i < 2; ++i) {
      int c = tid + 256 * i;
      int row = c >> 2;
      int coff = ((c & 3) ^ (row & 3) ^ ((row >> 2) & 3)) * 8;   // XOR swizzle
      _Float16* ldsA = (_Float16*)((char*)As + w * 1024 + i * 4096 + lane * 16);
      _Float16* ldsB = (_Float16*)((char*)Bs + w * 1024 + i * 4096 + lane * 16);
      async_copy16(Wn + (R0 + row) * DD + k0 + coff, ldsA);
      async_copy16(O  + (C0 + row) * DD + k0 + coff, ldsB);
    }
    __syncthreads();
    f16x8 af[4], bf[4];
    #pragma unroll
    for (int ri = 0; ri < 4; ++ri)
      af[ri] = *(const f16x8*)&As[swz_chunk(wr + ri * 16 + (lane & 15), lane >> 4) * 8];
    #pragma unroll
    for (int ci = 0; ci < 4; ++ci)
      bf[ci] = *(const f16x8*)&Bs[swz_chunk(wc + ci * 16 + (lane & 15), lane >> 4) * 8];
    #pragma unroll
    for (int ri = 0; ri < 4; ++ri)
      #pragma unroll
      for (int ci = 0; ci < 4; ++ci)
        acc[ri][ci] = __builtin_amdgcn_mfma_f32_16x16x32_f16(af[ri], bf[ci], acc[ri][ci], 0, 0, 0);
  }
  const int slab  = C0 >> 8;          // all 128 tokens of tile share one (b,t) slab
  const int sbase = C0 & 255;
  #pragma unroll
  for (int ri = 0; ri < 4; ++ri) {
    #pragma unroll
    for (int ci = 0; ci < 4; ++ci) {
      int s = sbase + wc + ci * 16 + (lane & 15);
      f32x4 v = acc[ri][ci];
      #pragma unroll
      for (int r = 0; r < 4; ++r) {
        int R = R0 + wr + ri * 16 + (lane >> 4) * 4 + r;
        out[(slab * DD + R) * SS + s] = v[r] + bo[R];   // 16 lanes -> 64B contiguous
      }
    }
  }
}

// ---------------------------------------------------------------------------
// host launcher.  ws layout (needs ~197 MiB):
//   [0)              A f16 [32768][768]   (reused as O after QKV GEMM)
//   [50331648)       WQKV f16 [2304][768]
//   [53870592)       Wo   f16 [768][768]
//   [55050240)       upen f32 [32768]
//   [55181312)       QKV  f16 [32768][2304]
// ---------------------------------------------------------------------------
extern "C" void kernel_launch(void* const* d_in, const int* in_sizes, int n_in,
                              void* d_out, int out_size, void* d_ws, size_t ws_size,
                              hipStream_t stream) {
  const float* h   = (const float*)d_in[0];
  const float* u   = (const float*)d_in[1];
  const float* lam = (const float*)d_in[2];
  const float* Wq  = (const float*)d_in[3];
  const float* bq  = (const float*)d_in[4];
  const float* Wk  = (const float*)d_in[5];
  const float* bk  = (const float*)d_in[6];
  const float* Wv  = (const float*)d_in[7];
  const float* bv  = (const float*)d_in[8];
  const float* Wo  = (const float*)d_in[9];
  const float* bo  = (const float*)d_in[10];
  float* out = (float*)d_out;

  char* ws = (char*)d_ws;
  _Float16* Abuf = (_Float16*)(ws);
  _Float16* WQKV = (_Float16*)(ws + 50331648);
  _Float16* WoH  = (_Float16*)(ws + 53870592);
  float*    upen = (float*)   (ws + 55050240);
  _Float16* QKV  = (_Float16*)(ws + 55181312);

  hipMemsetAsync(upen, 0, 32768 * sizeof(float), stream);
  k_transpose_h<<<dim3(128, 12), 256, 0, stream>>>(h, Abuf);
  k_convert_w<<<1152, 256, 0, stream>>>(Wq, Wk, Wv, Wo, WQKV, WoH);
  k_upen<<<512, 256, 0, stream>>>(u, lam, upen);
  k_gemm_qkv<<<256 * 18, 256, 0, stream>>>(Abuf, WQKV, bq, bk, bv, QKV);
  k_attn<<<1024 * 3, 256, 0, stream>>>(QKV, upen, Abuf);
  k_gemm_out<<<256 * 6, 256, 0, stream>>>(WoH, Abuf, bo, out);
}

// Round 3
// 533.678 us; speedup vs baseline: 1.0579x; 1.0004x over previous
//
#include <hip/hip_runtime.h>

typedef float   f32x4 __attribute__((ext_vector_type(4)));
typedef _Float16 f16x8 __attribute__((ext_vector_type(8)));

#define DEV static __device__ __forceinline__

// ---- problem constants ----
#define BB 4
#define TT 32
#define DD 768
#define SS 256          // Hp*Wp
#define NHD 12
#define HD 64
#define NSEQ  (BB*SS)   // 1024 sequences
#define MTOK  (NSEQ*TT) // 32768 tokens

DEV void async_copy16(const _Float16* g, _Float16* l) {
  __builtin_amdgcn_global_load_lds(
      (const __attribute__((address_space(1))) unsigned int*)g,
      (__attribute__((address_space(3))) unsigned int*)l,
      16, 0, 0);
}

// XOR-swizzled LDS 16B-chunk index for [rows][4 chunk] tiles (BK=32 f16).
DEV int swz_chunk(int r, int kc) {
  return r * 4 + (kc ^ (r & 3) ^ ((r >> 2) & 3));
}

// ---------------------------------------------------------------------------
// K0a: h (B,T,D,Hp,Wp) fp32 -> A[token][d] f16  (d<->s transpose via LDS)
// ---------------------------------------------------------------------------
__global__ __launch_bounds__(256) void k_transpose_h(const float* __restrict__ h,
                                                     _Float16* __restrict__ A) {
  __shared__ _Float16 Tl[256 * 65];
  const int slab = blockIdx.x;
  const int d0   = blockIdx.y * 64;
  const int t    = threadIdx.x;
  const float4* hv = (const float4*)(h + (slab * DD + d0) * SS);
  #pragma unroll
  for (int i = 0; i < 16; ++i) {
    int dd = i * 4 + (t >> 6);
    int s4 = (t & 63) * 4;
    float4 v = hv[dd * 64 + (t & 63)];
    Tl[(s4 + 0) * 65 + dd] = (_Float16)v.x;
    Tl[(s4 + 1) * 65 + dd] = (_Float16)v.y;
    Tl[(s4 + 2) * 65 + dd] = (_Float16)v.z;
    Tl[(s4 + 3) * 65 + dd] = (_Float16)v.w;
  }
  __syncthreads();
  #pragma unroll
  for (int p = 0; p < 8; ++p) {
    int s  = p * 32 + (t >> 3);
    int dd = (t & 7) * 8;
    f16x8 val;
    #pragma unroll
    for (int j = 0; j < 8; ++j) val[j] = Tl[s * 65 + dd + j];
    *(f16x8*)(A + (slab * SS + s) * DD + d0 + dd) = val;
  }
}

// ---------------------------------------------------------------------------
// K0b: weights fp32 -> f16
// ---------------------------------------------------------------------------
__global__ __launch_bounds__(256) void k_convert_w(const float* __restrict__ Wq,
                                                   const float* __restrict__ Wk,
                                                   const float* __restrict__ Wv,
                                                   const float* __restrict__ Wo,
                                                   _Float16* __restrict__ WQKV,
                                                   _Float16* __restrict__ WoH) {
  int idx = blockIdx.x * 256 + threadIdx.x;
  int row = idx / 96;
  int c8  = (idx % 96) * 8;
  const float* src; _Float16* dst;
  if (row < 768)       { src = Wq + row * 768;          dst = WQKV + row * 768; }
  else if (row < 1536) { src = Wk + (row - 768) * 768;  dst = WQKV + row * 768; }
  else if (row < 2304) { src = Wv + (row - 1536) * 768; dst = WQKV + row * 768; }
  else                 { src = Wo + (row - 2304) * 768; dst = WoH  + (row - 2304) * 768; }
  float4 v0 = *(const float4*)(src + c8);
  float4 v1 = *(const float4*)(src + c8 + 4);
  f16x8 o;
  o[0]=(_Float16)v0.x; o[1]=(_Float16)v0.y; o[2]=(_Float16)v0.z; o[3]=(_Float16)v0.w;
  o[4]=(_Float16)v1.x; o[5]=(_Float16)v1.y; o[6]=(_Float16)v1.z; o[7]=(_Float16)v1.w;
  *(f16x8*)(dst + c8) = o;
}

// ---------------------------------------------------------------------------
// K1: u_pen[(b*256+s)*32 + t] = lam * mean_d u
// ---------------------------------------------------------------------------
__global__ __launch_bounds__(256) void k_upen(const float* __restrict__ u,
                                              const float* __restrict__ lam,
                                              float* __restrict__ upen) {
  int slab = blockIdx.x >> 2;
  int q    = blockIdx.x & 3;
  int s    = threadIdx.x;
  const float* base = u + (slab * DD + q * 192) * SS + s;
  float sum = 0.f;
  for (int d = 0; d < 192; ++d) sum += base[d * SS];
  int b = slab >> 5, tt = slab & 31;
  float l = lam[slab * SS + s];
  atomicAdd(&upen[(b * SS + s) * TT + tt], sum * l * (1.0f / 768.0f));
}

// ---------------------------------------------------------------------------
// K2: QKV GEMM.  Block tile 128m x 256n, BK=32, 4 waves of 64x128.
// (wave-tile 64x128 cuts LDS-read bytes/FLOP 1.33x vs 64x64 — LDS-BW-bound.)
// Epilogue writes packed Qp/Kp/Vp[seq][head][t][hd], Q scaled by 1/8.
// mt-fastest: same-mt blocks share an XCD -> A-tile fetched once per XCD.
// ---------------------------------------------------------------------------
__global__ __launch_bounds__(256, 2) void k_gemm_qkv(const _Float16* __restrict__ A,
                                                     const _Float16* __restrict__ Bw,
                                                     const float* __restrict__ bq,
                                                     const float* __restrict__ bk,
                                                     const float* __restrict__ bv,
                                                     _Float16* __restrict__ Qp,
                                                     _Float16* __restrict__ Kp,
                                                     _Float16* __restrict__ Vp) {
  __shared__ _Float16 As[128 * 32];   // 512 chunks
  __shared__ _Float16 Bs[256 * 32];   // 1024 chunks
  const int mt = blockIdx.x & 255, nt = blockIdx.x >> 8;   // mt-fastest
  const int m0 = mt * 128, n0 = nt * 256;
  const int tid = threadIdx.x, w = tid >> 6, lane = tid & 63;
  const int wr = (w >> 1) * 64, wcc = (w & 1) * 128;
  f32x4 acc[4][8] = {};
  for (int it = 0; it < 24; ++it) {
    const int k0 = it * 32;
    __syncthreads();
    #pragma unroll
    for (int i = 0; i < 2; ++i) {      // A: 512 chunks
      int c = tid + 256 * i;
      int row = c >> 2;
      int coff = ((c & 3) ^ (row & 3) ^ ((row >> 2) & 3)) * 8;
      _Float16* ldsA = (_Float16*)((char*)As + (w * 1024 + i * 4096 + lane * 16));
      async_copy16(A + (m0 + row) * DD + k0 + coff, ldsA);
    }
    #pragma unroll
    for (int i = 0; i < 4; ++i) {      // B: 1024 chunks
      int c = tid + 256 * i;
      int row = c >> 2;
      int coff = ((c & 3) ^ (row & 3) ^ ((row >> 2) & 3)) * 8;
      _Float16* ldsB = (_Float16*)((char*)Bs + (w * 1024 + i * 4096 + lane * 16));
      async_copy16(Bw + (n0 + row) * DD + k0 + coff, ldsB);
    }
    __syncthreads();
    f16x8 af[4], bf[8];
    #pragma unroll
    for (int mi = 0; mi < 4; ++mi)
      af[mi] = *(const f16x8*)&As[swz_chunk(wr + mi * 16 + (lane & 15), lane >> 4) * 8];
    #pragma unroll
    for (int ni = 0; ni < 8; ++ni)
      bf[ni] = *(const f16x8*)&Bs[swz_chunk(wcc + ni * 16 + (lane & 15), lane >> 4) * 8];
    #pragma unroll
    for (int mi = 0; mi < 4; ++mi)
      #pragma unroll
      for (int ni = 0; ni < 8; ++ni)
        acc[mi][ni] = __builtin_amdgcn_mfma_f32_16x16x32_f16(af[mi], bf[ni], acc[mi][ni], 0, 0, 0);
  }
  // epilogue: n -> (sel, head, hd); m -> (b, t, s);  write packed [seq][head][t][hd]
  const int sel = nt / 3;                                   // 0=Q 1=K 2=V (block-uniform)
  const float scale = (sel == 0) ? 0.125f : 1.0f;           // fold 1/sqrt(64) into Q
  const float* bias = (sel == 0) ? bq : ((sel == 1) ? bk : bv);
  _Float16* dst = (sel == 0) ? Qp : ((sel == 1) ? Kp : Vp);
  const int slab = mt >> 1, s0 = (mt & 1) * 128;
  const int b = slab >> 5, t = slab & 31;
  #pragma unroll
  for (int ni = 0; ni < 8; ++ni) {
    int n768 = nt * 256 - sel * 768 + wcc + ni * 16 + (lane & 15);
    int head = n768 >> 6, hd = n768 & 63;
    float bs = bias[n768];
    long hb = (long)head * 2048 + t * 64 + hd;
    #pragma unroll
    for (int mi = 0; mi < 4; ++mi) {
      f32x4 v = acc[mi][ni];
      #pragma unroll
      for (int r = 0; r < 4; ++r) {
        int s = s0 + wr + mi * 16 + (lane >> 4) * 4 + r;
        long seq = b * 256 + s;
        dst[seq * 24576 + hb] = (_Float16)((v[r] + bs) * scale);
      }
    }
  }
}

// ---------------------------------------------------------------------------
// K3: attention v2. 1 wave per (seq, head); all global reads dense 4KB blocks.
// V transposed through per-wave LDS (stride 66: both sides 2-way = free).
// O written token-major into Abuf for the output GEMM.
// ---------------------------------------------------------------------------
__global__ __launch_bounds__(256) void k_attn(const _Float16* __restrict__ Qp,
                                              const _Float16* __restrict__ Kp,
                                              const _Float16* __restrict__ Vp,
                                              const float* __restrict__ upen,
                                              _Float16* __restrict__ O) {
  __shared__ _Float16 lds[4][32 * 66 + 32 * 40];   // per-wave: Vs[32][66], Ps[32][40]
  const int w = threadIdx.x >> 6, lane = threadIdx.x & 63;
  const int seq = blockIdx.x / 3, hg = blockIdx.x % 3;
  const int head = hg * 4 + w;
  const int b = seq >> 8, s = seq & 255;
  _Float16* Vs = &lds[w][0];
  _Float16* Ps = &lds[w][32 * 66];
  const long base = (long)(seq * NHD + head) * 2048;
  const _Float16* Qb = Qp + base;
  const _Float16* Kb = Kp + base;
  const _Float16* Vb = Vp + base;

  // stage V (dense 4KB) -> LDS stride 66, f16x2 writes (2-way, free)
  {
    int t = lane & 31, hh = (lane >> 5) * 32;
    f16x8 vc[4];
    #pragma unroll
    for (int c = 0; c < 4; ++c) vc[c] = *(const f16x8*)(Vb + t * 64 + hh + c * 8);
    #pragma unroll
    for (int c = 0; c < 4; ++c)
      #pragma unroll
      for (int p = 0; p < 4; ++p) {
        union { _Float16 h[2]; unsigned u; } pk;
        pk.h[0] = vc[c][2 * p]; pk.h[1] = vc[c][2 * p + 1];
        *(unsigned*)&Vs[t * 66 + hh + c * 8 + 2 * p] = pk.u;
      }
  }
  // Q/K fragments direct from global (dense within the 4KB block)
  f16x8 qf[2][2], kf[2][2];
  #pragma unroll
  for (int i = 0; i < 2; ++i)
    #pragma unroll
    for (int ks = 0; ks < 2; ++ks) {
      int off = (i * 16 + (lane & 15)) * 64 + ks * 32 + (lane >> 4) * 8;
      qf[i][ks] = *(const f16x8*)(Qb + off);
      kf[i][ks] = *(const f16x8*)(Kb + off);
    }
  // scores = (Q/8) . K^T
  f32x4 sc[2][2] = {};
  #pragma unroll
  for (int mq = 0; mq < 2; ++mq)
    #pragma unroll
    for (int nk = 0; nk < 2; ++nk)
      #pragma unroll
      for (int ks = 0; ks < 2; ++ks)
        sc[mq][nk] = __builtin_amdgcn_mfma_f32_16x16x32_f16(qf[mq][ks], kf[nk][ks], sc[mq][nk], 0, 0, 0);

  const float up0 = upen[seq * TT + (lane & 15)];
  const float up1 = upen[seq * TT + 16 + (lane & 15)];

  // softmax over 32 keys per query row
  #pragma unroll
  for (int mq = 0; mq < 2; ++mq) {
    #pragma unroll
    for (int r = 0; r < 4; ++r) {
      float s0 = sc[mq][0][r] - up0;
      float s1 = sc[mq][1][r] - up1;
      float mx = fmaxf(s0, s1);
      #pragma unroll
      for (int off = 1; off < 16; off <<= 1) mx = fmaxf(mx, __shfl_xor(mx, off, 64));
      float e0 = __expf(s0 - mx), e1 = __expf(s1 - mx);
      float sum = e0 + e1;
      #pragma unroll
      for (int off = 1; off < 16; off <<= 1) sum += __shfl_xor(sum, off, 64);
      float inv = 1.0f / sum;
      int row = mq * 16 + (lane >> 4) * 4 + r;
      Ps[row * 40 + (lane & 15)]      = (_Float16)(e0 * inv);
      Ps[row * 40 + 16 + (lane & 15)] = (_Float16)(e1 * inv);
    }
  }
  // PV
  f16x8 pf[2];
  #pragma unroll
  for (int mq = 0; mq < 2; ++mq)
    pf[mq] = *(const f16x8*)(Ps + (mq * 16 + (lane & 15)) * 40 + (lane >> 4) * 8);
  f32x4 oacc[2][4] = {};
  #pragma unroll
  for (int nh = 0; nh < 4; ++nh) {
    int hd = nh * 16 + (lane & 15);
    f16x8 vf;
    #pragma unroll
    for (int j = 0; j < 8; ++j) vf[j] = Vs[((lane >> 4) * 8 + j) * 66 + hd];  // 2-way, free
    #pragma unroll
    for (int mq = 0; mq < 2; ++mq)
      oacc[mq][nh] = __builtin_amdgcn_mfma_f32_16x16x32_f16(pf[mq], vf, oacc[mq][nh], 0, 0, 0);
  }
  // write O token-major [m][768]
  #pragma unroll
  for (int mq = 0; mq < 2; ++mq)
    #pragma unroll
    for (int nh = 0; nh < 4; ++nh) {
      int hd = nh * 16 + (lane & 15);
      #pragma unroll
      for (int r = 0; r < 4; ++r) {
        int t = mq * 16 + (lane >> 4) * 4 + r;
        O[((long)((b << 5) + t) * SS + s) * DD + head * HD + hd] = (_Float16)oacc[mq][nh][r];
      }
    }
}

// ---------------------------------------------------------------------------
// K4: output GEMM, swapped operands: C'[R][token] = Wo[R][:] . O[token][:]
// Block tile 128R x 256tok, 4 waves of 64x128. ct-fastest for XCD locality.
// Writes final (B,T,D,Hp,Wp) fp32 with s-contiguous coalesced stores.
// ---------------------------------------------------------------------------
__global__ __launch_bounds__(256, 2) void k_gemm_out(const _Float16* __restrict__ Wn,
                                                     const _Float16* __restrict__ O,
                                                     const float* __restrict__ bo,
                                                     float* __restrict__ out) {
  __shared__ _Float16 As[128 * 32];   // Wo rows
  __shared__ _Float16 Bs[256 * 32];   // O token rows
  const int ct = blockIdx.x & 127, rt = blockIdx.x >> 7;   // ct-fastest
  const int R0 = rt * 128, C0 = ct * 256;
  const int tid = threadIdx.x, w = tid >> 6, lane = tid & 63;
  const int wr = (w >> 1) * 64, wcc = (w & 1) * 128;
  f32x4 acc[4][8] = {};
  for (int it = 0; it < 24; ++it) {
    const int k0 = it * 32;
    __syncthreads();
    #pragma unroll
    for (int i = 0; i < 2; ++i) {
      int c = tid + 256 * i;
      int row = c >> 2;
      int coff = ((c & 3) ^ (row & 3) ^ ((row >> 2) & 3)) * 8;
      _Float16* ldsA = (_Float16*)((char*)As + (w * 1024 + i * 4096 + lane * 16));
      async_copy16(Wn + (R0 + row) * DD + k0 + coff, ldsA);
    }
    #pragma unroll
    for (int i = 0; i < 4; ++i) {
      int c = tid + 256 * i;
      int row = c >> 2;
      int coff = ((c & 3) ^ (row & 3) ^ ((row >> 2) & 3)) * 8;
      _Float16* ldsB = (_Float16*)((char*)Bs + (w * 1024 + i * 4096 + lane * 16));
      async_copy16(O + (C0 + row) * DD + k0 + coff, ldsB);
    }
    __syncthreads();
    f16x8 af[4], bf[8];
    #pragma unroll
    for (int ri = 0; ri < 4; ++ri)
      af[ri] = *(const f16x8*)&As[swz_chunk(wr + ri * 16 + (lane & 15), lane >> 4) * 8];
    #pragma unroll
    for (int ci = 0; ci < 8; ++ci)
      bf[ci] = *(const f16x8*)&Bs[swz_chunk(wcc + ci * 16 + (lane & 15), lane >> 4) * 8];
    #pragma unroll
    for (int ri = 0; ri < 4; ++ri)
      #pragma unroll
      for (int ci = 0; ci < 8; ++ci)
        acc[ri][ci] = __builtin_amdgcn_mfma_f32_16x16x32_f16(af[ri], bf[ci], acc[ri][ci], 0, 0, 0);
  }
  const int slab = ct;                 // C-tile = all 256 tokens of one slab
  #pragma unroll
  for (int ri = 0; ri < 4; ++ri) {
    #pragma unroll
    for (int ci = 0; ci < 8; ++ci) {
      int s = wcc + ci * 16 + (lane & 15);
      f32x4 v = acc[ri][ci];
      #pragma unroll
      for (int r = 0; r < 4; ++r) {
        int R = R0 + wr + ri * 16 + (lane >> 4) * 4 + r;
        out[((long)slab * DD + R) * SS + s] = v[r] + bo[R];
      }
    }
  }
}

// ---------------------------------------------------------------------------
// host launcher.  ws layout (~197 MiB):
//   [0)          A f16 [32768][768]  (reused as O after attention)
//   [50331648)   WQKV f16 [2304][768]
//   [53870592)   Wo   f16 [768][768]
//   [55050240)   upen f32 [32768]
//   [55181312)   Qp f16 [1024][12][32][64]
//   [105512960)  Kp f16  (same shape)
//   [155844608)  Vp f16  (same shape)   end 206176256
// ---------------------------------------------------------------------------
extern "C" void kernel_launch(void* const* d_in, const int* in_sizes, int n_in,
                              void* d_out, int out_size, void* d_ws, size_t ws_size,
                              hipStream_t stream) {
  const float* h   = (const float*)d_in[0];
  const float* u   = (const float*)d_in[1];
  const float* lam = (const float*)d_in[2];
  const float* Wq  = (const float*)d_in[3];
  const float* bq  = (const float*)d_in[4];
  const float* Wk  = (const float*)d_in[5];
  const float* bk  = (const float*)d_in[6];
  const float* Wv  = (const float*)d_in[7];
  const float* bv  = (const float*)d_in[8];
  const float* Wo  = (const float*)d_in[9];
  const float* bo  = (const float*)d_in[10];
  float* out = (float*)d_out;

  char* ws = (char*)d_ws;
  _Float16* Abuf = (_Float16*)(ws);
  _Float16* WQKV = (_Float16*)(ws + 50331648);
  _Float16* WoH  = (_Float16*)(ws + 53870592);
  float*    upen = (float*)   (ws + 55050240);
  _Float16* Qp   = (_Float16*)(ws + 55181312);
  _Float16* Kp   = (_Float16*)(ws + 105512960);
  _Float16* Vp   = (_Float16*)(ws + 155844608);

  hipMemsetAsync(upen, 0, 32768 * sizeof(float), stream);
  k_transpose_h<<<dim3(128, 12), 256, 0, stream>>>(h, Abuf);
  k_convert_w<<<1152, 256, 0, stream>>>(Wq, Wk, Wv, Wo, WQKV, WoH);
  k_upen<<<512, 256, 0, stream>>>(u, lam, upen);
  k_gemm_qkv<<<256 * 9, 256, 0, stream>>>(Abuf, WQKV, bq, bk, bv, Qp, Kp, Vp);
  k_attn<<<1024 * 3, 256, 0, stream>>>(Qp, Kp, Vp, upen, Abuf);
  k_gemm_out<<<128 * 6, 256, 0, stream>>>(WoH, Abuf, bo, out);
}